// Round 1
// baseline (327.974 us; speedup 1.0000x reference)
//
#include <hip/hip_runtime.h>
#include <hip/hip_bf16.h>

#define NN 16384
#define DD 256

typedef unsigned short u16;
typedef unsigned int u32;
typedef __attribute__((ext_vector_type(8))) __bf16 bf16x8;
typedef __attribute__((ext_vector_type(4))) float f32x4;

// ---------- helpers ----------
static __device__ __forceinline__ u16 f2bf(float f) {
    u32 u = __float_as_uint(f);
    u32 r = (u + 0x7fffu + ((u >> 16) & 1u)) >> 16;   // RNE
    return (u16)r;
}
static __device__ __forceinline__ float bf2f(u16 u) {
    return __uint_as_float(((u32)u) << 16);
}

// ---------- kernel 1: convert to bf16 (image scaled by log2(e)), zero sums ----------
__global__ void prep_kernel(const float* __restrict__ img, const float* __restrict__ txt,
                            u16* __restrict__ Abf, u16* __restrict__ Bbf,
                            float* __restrict__ zbuf /* s_row..s_col, 32768 floats */) {
    int gid = blockIdx.x * 256 + threadIdx.x;          // 0 .. 1048575  (N*D/4)
    float4 va = ((const float4*)img)[gid];
    float4 vb = ((const float4*)txt)[gid];
    ushort4 ua, ub;
    const float S = 1.44269504088896f;                  // log2(e)
    ua.x = f2bf(va.x * S); ua.y = f2bf(va.y * S); ua.z = f2bf(va.z * S); ua.w = f2bf(va.w * S);
    ub.x = f2bf(vb.x);     ub.y = f2bf(vb.y);     ub.z = f2bf(vb.z);     ub.w = f2bf(vb.w);
    ((ushort4*)Abf)[gid] = ua;
    ((ushort4*)Bbf)[gid] = ub;
    if (gid < 32768) zbuf[gid] = 0.0f;
}

// ---------- kernel 2: diagonal logits (log2-scaled), one wave per row ----------
__global__ void diag_kernel(const u16* __restrict__ Abf, const u16* __restrict__ Bbf,
                            float* __restrict__ diag) {
    int t = threadIdx.x;
    int lane = t & 63;
    int wid = t >> 6;
    int row = blockIdx.x * 4 + wid;
    const ushort4 a = *(const ushort4*)(Abf + (size_t)row * DD + lane * 4);
    const ushort4 b = *(const ushort4*)(Bbf + (size_t)row * DD + lane * 4);
    float s = bf2f(a.x) * bf2f(b.x) + bf2f(a.y) * bf2f(b.y)
            + bf2f(a.z) * bf2f(b.z) + bf2f(a.w) * bf2f(b.w);
    #pragma unroll
    for (int off = 1; off < 64; off <<= 1) s += __shfl_xor(s, off, 64);
    if (lane == 0) diag[row] = s;
}

// ---------- kernel 3: fused GEMM + exp2 + row/col sum ----------
// tile 128x128, 4 waves (2x2), each wave 4x4 of 16x16x32 bf16 MFMAs, BK=64
__global__ __launch_bounds__(256, 3) void gemm_lse_kernel(
        const u16* __restrict__ Abf, const u16* __restrict__ Bbf,
        float* __restrict__ s_row, float* __restrict__ s_col) {
    __shared__ u16 sA[128 * 72];      // +8 pad: 2-way bank aliasing (free)
    __shared__ u16 sB[128 * 72];
    __shared__ float red_r[128];
    __shared__ float red_c[128];

    const int t = threadIdx.x;
    const int lane = t & 63;
    const int wid = t >> 6;
    const int wr = wid >> 1, wc = wid & 1;
    const int q = lane >> 4, m = lane & 15;
    const int bi = blockIdx.x & 127;            // row tile (fast: consecutive blocks share B)
    const int bj = blockIdx.x >> 7;
    const int row0 = bi << 7, col0 = bj << 7;

    if (t < 128) red_r[t] = 0.0f; else red_c[t - 128] = 0.0f;

    const f32x4 fzero = {0.f, 0.f, 0.f, 0.f};
    f32x4 acc[4][4];
    #pragma unroll
    for (int a = 0; a < 4; ++a)
        #pragma unroll
        for (int b = 0; b < 4; ++b) acc[a][b] = fzero;

    for (int kc = 0; kc < 4; ++kc) {
        const int kb = kc << 6;
        __syncthreads();
        #pragma unroll
        for (int i = 0; i < 4; ++i) {
            int fc = (i << 8) + t;              // 0..1023
            int r  = fc >> 3;
            int c8 = fc & 7;
            uint4 va = *(const uint4*)(Abf + (size_t)(row0 + r) * DD + kb + (c8 << 3));
            *(uint4*)(&sA[r * 72 + (c8 << 3)]) = va;
            uint4 vb = *(const uint4*)(Bbf + (size_t)(col0 + r) * DD + kb + (c8 << 3));
            *(uint4*)(&sB[r * 72 + (c8 << 3)]) = vb;
        }
        __syncthreads();
        #pragma unroll
        for (int s = 0; s < 2; ++s) {
            const int k8 = (s << 2) + q;        // k = kb + k8*8 + j  (A[m][k=q*8+j] layout)
            bf16x8 af[4], bfv[4];
            #pragma unroll
            for (int rb = 0; rb < 4; ++rb) {
                int rr = (wr << 6) + (rb << 4) + m;
                af[rb]  = *(const bf16x8*)(&sA[rr * 72 + (k8 << 3)]);
                int cc = (wc << 6) + (rb << 4) + m;
                bfv[rb] = *(const bf16x8*)(&sB[cc * 72 + (k8 << 3)]);
            }
            #pragma unroll
            for (int rb = 0; rb < 4; ++rb)
                #pragma unroll
                for (int cb = 0; cb < 4; ++cb)
                    acc[rb][cb] = __builtin_amdgcn_mfma_f32_16x16x32_bf16(
                        af[rb], bfv[cb], acc[rb][cb], 0, 0, 0);
        }
    }

    // epilogue: exp2(l' - 144) in place; D layout: col = m, row = q*4 + reg
    #pragma unroll
    for (int rb = 0; rb < 4; ++rb)
        #pragma unroll
        for (int cb = 0; cb < 4; ++cb)
            #pragma unroll
            for (int r = 0; r < 4; ++r)
                acc[rb][cb][r] = __builtin_amdgcn_exp2f(acc[rb][cb][r] - 144.0f);

    // row sums: sum over cols. For each (rb, reg): reduce 4 cb + 16 lanes of quad.
    float rpart = 0.0f;
    #pragma unroll
    for (int rb = 0; rb < 4; ++rb)
        #pragma unroll
        for (int r = 0; r < 4; ++r) {
            float v = acc[rb][0][r] + acc[rb][1][r] + acc[rb][2][r] + acc[rb][3][r];
            v += __shfl_xor(v, 1, 16);
            v += __shfl_xor(v, 2, 16);
            v += __shfl_xor(v, 4, 16);
            v += __shfl_xor(v, 8, 16);
            if (m == ((rb << 2) | r)) rpart = v;   // lane m keeps (rb=m>>2, r=m&3), its own q
        }
    // row_in_tile = wr*64 + rb*16 + q*4 + r
    atomicAdd(&red_r[(wr << 6) + ((m >> 2) << 4) + (q << 2) + (m & 3)], rpart);

    // col sums: sum over rows. For each cb: 16 in-lane adds + butterfly across quads.
    float cpart = 0.0f;
    #pragma unroll
    for (int cb = 0; cb < 4; ++cb) {
        float v = 0.0f;
        #pragma unroll
        for (int rb = 0; rb < 4; ++rb)
            v += acc[rb][cb][0] + acc[rb][cb][1] + acc[rb][cb][2] + acc[rb][cb][3];
        v += __shfl_xor(v, 16, 64);
        v += __shfl_xor(v, 32, 64);
        if (q == cb) cpart = v;                   // lane keeps cb=q, col = wc*64 + q*16 + m
    }
    atomicAdd(&red_c[(wc << 6) + (q << 4) + m], cpart);

    __syncthreads();
    if (t < 128) atomicAdd(&s_row[row0 + t], red_r[t]);
    else         atomicAdd(&s_col[col0 + (t - 128)], red_c[t - 128]);
}

// ---------- kernel 4: final reduce ----------
__global__ void final_kernel(const float* __restrict__ s_row, const float* __restrict__ s_col,
                             const float* __restrict__ diag, float* __restrict__ out) {
    __shared__ double red[256];
    int t = threadIdx.x;
    double p = 0.0;
    for (int i = t; i < NN; i += 256) {
        p += 0.5 * (double)(log2f(s_row[i]) + log2f(s_col[i])) + 144.0 - (double)diag[i];
    }
    red[t] = p;
    __syncthreads();
    for (int s = 128; s > 0; s >>= 1) {
        if (t < s) red[t] += red[t + s];
        __syncthreads();
    }
    if (t == 0) out[0] = (float)(red[0] * 0.6931471805599453 / (double)NN);
}

// ---------- launch ----------
extern "C" void kernel_launch(void* const* d_in, const int* in_sizes, int n_in,
                              void* d_out, int out_size, void* d_ws, size_t ws_size,
                              hipStream_t stream) {
    const float* img = (const float*)d_in[0];
    const float* txt = (const float*)d_in[1];
    char* ws = (char*)d_ws;
    u16*   Abf   = (u16*)ws;                               // 8 MB
    u16*   Bbf   = (u16*)(ws + 8388608);                   // 8 MB
    float* s_row = (float*)(ws + 16777216);                // 64 KB
    float* s_col = (float*)(ws + 16777216 + 65536);        // 64 KB
    float* diag  = (float*)(ws + 16777216 + 131072);       // 64 KB
    float* out   = (float*)d_out;

    prep_kernel<<<4096, 256, 0, stream>>>(img, txt, Abf, Bbf, s_row);
    diag_kernel<<<4096, 256, 0, stream>>>(Abf, Bbf, diag);
    gemm_lse_kernel<<<16384, 256, 0, stream>>>(Abf, Bbf, s_row, s_col);
    final_kernel<<<1, 256, 0, stream>>>(s_row, s_col, diag, out);
}

// Round 2
// 310.705 us; speedup vs baseline: 1.0556x; 1.0556x over previous
//
#include <hip/hip_runtime.h>
#include <hip/hip_bf16.h>

#define NN 16384
#define DD 256

typedef unsigned short u16;
typedef unsigned int u32;
typedef __attribute__((ext_vector_type(8))) __bf16 bf16x8;
typedef __attribute__((ext_vector_type(4))) float f32x4;

// ---------- helpers ----------
static __device__ __forceinline__ u16 f2bf(float f) {
    u32 u = __float_as_uint(f);
    u32 r = (u + 0x7fffu + ((u >> 16) & 1u)) >> 16;   // RNE
    return (u16)r;
}

// async global->LDS, 16B per lane; LDS dest = wave-uniform base + lane*16
static __device__ __forceinline__ void gload16(const u16* g, u16* l) {
    __builtin_amdgcn_global_load_lds(
        (const __attribute__((address_space(1))) void*)g,
        (__attribute__((address_space(3))) void*)l,
        16, 0, 0);
}

// ---------- kernel 1: convert to bf16 (image scaled by log2(e)), zero sums ----------
__global__ void prep_kernel(const float* __restrict__ img, const float* __restrict__ txt,
                            u16* __restrict__ Abf, u16* __restrict__ Bbf,
                            float* __restrict__ zbuf /* s_row..s_col, 32768 floats */) {
    int gid = blockIdx.x * 256 + threadIdx.x;          // 0 .. 1048575  (N*D/4)
    float4 va = ((const float4*)img)[gid];
    float4 vb = ((const float4*)txt)[gid];
    ushort4 ua, ub;
    const float S = 1.44269504088896f;                  // log2(e)
    ua.x = f2bf(va.x * S); ua.y = f2bf(va.y * S); ua.z = f2bf(va.z * S); ua.w = f2bf(va.w * S);
    ub.x = f2bf(vb.x);     ub.y = f2bf(vb.y);     ub.z = f2bf(vb.z);     ub.w = f2bf(vb.w);
    ((ushort4*)Abf)[gid] = ua;
    ((ushort4*)Bbf)[gid] = ub;
    if (gid < 32768) zbuf[gid] = 0.0f;
}

// ---------- kernel 2: fused GEMM + exp2 + row/col sum + diag extraction ----------
// tile 128x128, 4 waves (2x2), each wave 4x4 of 16x16x32 bf16 MFMAs, BK=64
// LDS layout: unpadded 128B rows, chunk XOR-swizzled: LDS(row, c) holds global
// chunk c ^ (row & 7). global_load_lds writes lane l -> (base_row + l>>3, l&7).
__global__ __launch_bounds__(256, 4) void gemm_lse_kernel(
        const u16* __restrict__ Abf, const u16* __restrict__ Bbf,
        float* __restrict__ s_row, float* __restrict__ s_col,
        float* __restrict__ diag) {
    __shared__ u16 sA[128 * 64];
    __shared__ u16 sB[128 * 64];
    __shared__ float red_r[128];
    __shared__ float red_c[128];

    const int t = threadIdx.x;
    const int lane = t & 63;
    const int w = t >> 6;
    const int wr = w >> 1, wc = w & 1;
    const int q = lane >> 4, m = lane & 15;
    const int bi = blockIdx.x & 127;            // row tile fast: consecutive blocks share B panel
    const int bj = blockIdx.x >> 7;
    const int row0 = bi << 7, col0 = bj << 7;

    if (t < 128) red_r[t] = 0.0f; else red_c[t - 128] = 0.0f;

    // staging decomposition: wave w covers rows [w*32, w*32+32), 4 issues of 8 rows
    const int srow = w << 5;
    const int lr = lane >> 3;       // row within 8-row group
    const int cc8 = lane & 7;       // LDS chunk within row
    // swizzled global chunk: g = c ^ (row & 7); row & 7 == lr here
    const int gch = cc8 ^ lr;

    const f32x4 fzero = {0.f, 0.f, 0.f, 0.f};
    f32x4 acc[4][4];
    #pragma unroll
    for (int a = 0; a < 4; ++a)
        #pragma unroll
        for (int b = 0; b < 4; ++b) acc[a][b] = fzero;

    for (int kc = 0; kc < 4; ++kc) {
        const int kb = kc << 6;
        __syncthreads();
        #pragma unroll
        for (int j = 0; j < 4; ++j) {
            const int r = srow + (j << 3) + lr;
            const size_t goff = (size_t)r * DD + kb + (gch << 3);
            gload16((u16*)(Abf + (size_t)row0 * DD + goff), &sA[(srow + (j << 3)) << 6]);
            gload16((u16*)(Bbf + (size_t)col0 * DD + goff), &sB[(srow + (j << 3)) << 6]);
        }
        __syncthreads();    // drains vmcnt -> LDS tiles complete
        #pragma unroll
        for (int s = 0; s < 2; ++s) {
            const int k8 = (s << 2) + q;        // chunk index 0..7; k = kb + k8*8 + j
            bf16x8 af[4], bfv[4];
            #pragma unroll
            for (int rb = 0; rb < 4; ++rb) {
                const int rr = (wr << 6) + (rb << 4) + m;
                af[rb]  = *(const bf16x8*)(&sA[(rr << 6) + ((k8 ^ (m & 7)) << 3)]);
                const int ccr = (wc << 6) + (rb << 4) + m;
                bfv[rb] = *(const bf16x8*)(&sB[(ccr << 6) + ((k8 ^ (m & 7)) << 3)]);
            }
            #pragma unroll
            for (int rb = 0; rb < 4; ++rb)
                #pragma unroll
                for (int cb = 0; cb < 4; ++cb)
                    acc[rb][cb] = __builtin_amdgcn_mfma_f32_16x16x32_bf16(
                        af[rb], bfv[cb], acc[rb][cb], 0, 0, 0);
        }
    }

    // diag extraction (pre-exp, log2-scaled logits). D layout: col=m, row=q*4+r.
    // row==col requires wr==wc, rb==cb, m==q*4+r.
    if (bi == bj && wr == wc) {
        #pragma unroll
        for (int rb = 0; rb < 4; ++rb)
            #pragma unroll
            for (int r = 0; r < 4; ++r)
                if (m == ((q << 2) | r))
                    diag[row0 + (wr << 6) + (rb << 4) + m] = acc[rb][rb][r];
    }

    // epilogue: exp2(l' - 144) in place
    #pragma unroll
    for (int rb = 0; rb < 4; ++rb)
        #pragma unroll
        for (int cb = 0; cb < 4; ++cb)
            #pragma unroll
            for (int r = 0; r < 4; ++r)
                acc[rb][cb][r] = __builtin_amdgcn_exp2f(acc[rb][cb][r] - 144.0f);

    // row sums: sum over cols. For each (rb, reg): reduce 4 cb + 16 lanes of quad.
    float rpart = 0.0f;
    #pragma unroll
    for (int rb = 0; rb < 4; ++rb)
        #pragma unroll
        for (int r = 0; r < 4; ++r) {
            float v = acc[rb][0][r] + acc[rb][1][r] + acc[rb][2][r] + acc[rb][3][r];
            v += __shfl_xor(v, 1, 16);
            v += __shfl_xor(v, 2, 16);
            v += __shfl_xor(v, 4, 16);
            v += __shfl_xor(v, 8, 16);
            if (m == ((rb << 2) | r)) rpart = v;   // lane m keeps (rb=m>>2, r=m&3), its own q
        }
    // row_in_tile = wr*64 + rb*16 + q*4 + r
    atomicAdd(&red_r[(wr << 6) + ((m >> 2) << 4) + (q << 2) + (m & 3)], rpart);

    // col sums: sum over rows. For each cb: 16 in-lane adds + butterfly across quads.
    float cpart = 0.0f;
    #pragma unroll
    for (int cb = 0; cb < 4; ++cb) {
        float v = 0.0f;
        #pragma unroll
        for (int rb = 0; rb < 4; ++rb)
            v += acc[rb][cb][0] + acc[rb][cb][1] + acc[rb][cb][2] + acc[rb][cb][3];
        v += __shfl_xor(v, 16, 64);
        v += __shfl_xor(v, 32, 64);
        if (q == cb) cpart = v;                   // lane keeps cb=q, col = wc*64 + q*16 + m
    }
    atomicAdd(&red_c[(wc << 6) + (q << 4) + m], cpart);

    __syncthreads();
    if (t < 128) atomicAdd(&s_row[row0 + t], red_r[t]);
    else         atomicAdd(&s_col[col0 + (t - 128)], red_c[t - 128]);
}

// ---------- kernel 3: final reduce ----------
__global__ void final_kernel(const float* __restrict__ s_row, const float* __restrict__ s_col,
                             const float* __restrict__ diag, float* __restrict__ out) {
    __shared__ double red[256];
    int t = threadIdx.x;
    double p = 0.0;
    for (int i = t; i < NN; i += 256) {
        p += 0.5 * (double)(log2f(s_row[i]) + log2f(s_col[i])) + 144.0 - (double)diag[i];
    }
    red[t] = p;
    __syncthreads();
    for (int s = 128; s > 0; s >>= 1) {
        if (t < s) red[t] += red[t + s];
        __syncthreads();
    }
    if (t == 0) out[0] = (float)(red[0] * 0.6931471805599453 / (double)NN);
}

// ---------- launch ----------
extern "C" void kernel_launch(void* const* d_in, const int* in_sizes, int n_in,
                              void* d_out, int out_size, void* d_ws, size_t ws_size,
                              hipStream_t stream) {
    const float* img = (const float*)d_in[0];
    const float* txt = (const float*)d_in[1];
    char* ws = (char*)d_ws;
    u16*   Abf   = (u16*)ws;                               // 8 MB
    u16*   Bbf   = (u16*)(ws + 8388608);                   // 8 MB
    float* s_row = (float*)(ws + 16777216);                // 64 KB
    float* s_col = (float*)(ws + 16777216 + 65536);        // 64 KB
    float* diag  = (float*)(ws + 16777216 + 131072);       // 64 KB
    float* out   = (float*)d_out;

    prep_kernel<<<4096, 256, 0, stream>>>(img, txt, Abf, Bbf, s_row);
    gemm_lse_kernel<<<16384, 256, 0, stream>>>(Abf, Bbf, s_row, s_col, diag);
    final_kernel<<<1, 256, 0, stream>>>(s_row, s_col, diag, out);
}

// Round 3
// 309.808 us; speedup vs baseline: 1.0586x; 1.0029x over previous
//
#include <hip/hip_runtime.h>
#include <hip/hip_bf16.h>

#define NN 16384
#define DD 256

typedef unsigned short u16;
typedef unsigned int u32;
typedef __attribute__((ext_vector_type(8))) __bf16 bf16x8;
typedef __attribute__((ext_vector_type(4))) float f32x4;

// ---------- helpers ----------
static __device__ __forceinline__ u16 f2bf(float f) {
    u32 u = __float_as_uint(f);
    u32 r = (u + 0x7fffu + ((u >> 16) & 1u)) >> 16;   // RNE
    return (u16)r;
}

// async global->LDS, 16B per lane; LDS dest = wave-uniform base + lane*16
static __device__ __forceinline__ void gload16(const u16* g, u16* l) {
    __builtin_amdgcn_global_load_lds(
        (const __attribute__((address_space(1))) void*)g,
        (__attribute__((address_space(3))) void*)l,
        16, 0, 0);
}

// ---------- kernel 1: convert to bf16 (image scaled by log2(e)), zero sums ----------
__global__ void prep_kernel(const float* __restrict__ img, const float* __restrict__ txt,
                            u16* __restrict__ Abf, u16* __restrict__ Bbf,
                            float* __restrict__ zbuf /* s_row..s_col, 32768 floats */) {
    int gid = blockIdx.x * 256 + threadIdx.x;          // 0 .. 1048575  (N*D/4)
    float4 va = ((const float4*)img)[gid];
    float4 vb = ((const float4*)txt)[gid];
    ushort4 ua, ub;
    const float S = 1.44269504088896f;                  // log2(e)
    ua.x = f2bf(va.x * S); ua.y = f2bf(va.y * S); ua.z = f2bf(va.z * S); ua.w = f2bf(va.w * S);
    ub.x = f2bf(vb.x);     ub.y = f2bf(vb.y);     ub.z = f2bf(vb.z);     ub.w = f2bf(vb.w);
    ((ushort4*)Abf)[gid] = ua;
    ((ushort4*)Bbf)[gid] = ub;
    if (gid < 32768) zbuf[gid] = 0.0f;
}

// ---------- kernel 2: fused GEMM + exp2 + row/col sum + diag ----------
// Grid: 1024 blocks = 128 bi x 8 jg. Block: 128-row tile, j-loop over 16
// column tiles (cols jg*2048 .. +2048). A operand in REGISTERS (32 bf16x8 per
// lane), loaded once. B streamed through double-buffered LDS (2 x 16 KB),
// XOR-swizzled chunks (round-2 scheme, 0 conflicts). One barrier per K-chunk;
// prefetch of chunk g+1 is issued before compute of chunk g, so the vmcnt
// drain at the barrier lands after ~MFMA-compute worth of latency hiding.
__global__ __launch_bounds__(256, 2) void gemm_lse_kernel(
        const u16* __restrict__ Abf, const u16* __restrict__ Bbf,
        float* __restrict__ s_row, float* __restrict__ s_col,
        float* __restrict__ diag) {
    __shared__ u16 sB[2][128 * 64];

    const int t = threadIdx.x;
    const int lane = t & 63;
    const int w = t >> 6;
    const int wr = w >> 1, wc = w & 1;
    const int q = lane >> 4, m = lane & 15;
    const int bi = blockIdx.x & 127;
    const int jg = blockIdx.x >> 7;
    const int row0 = bi << 7;

    // B staging decomposition: wave w covers tile-rows [w*32, w*32+32)
    const int srow = w << 5;
    const int lr = lane >> 3;       // row within 8-row group
    const int cc8 = lane & 7;       // LDS chunk within row
    const int gch = cc8 ^ lr;       // swizzled global chunk (row&7 == lr)

    // ---- A operand -> registers: Areg[rb][i] covers row (wr*64+rb*16+m),
    // k in [(q+4i)*8, +8). Exactly the fragments this lane ever needs.
    bf16x8 Areg[4][8];
    #pragma unroll
    for (int rb = 0; rb < 4; ++rb) {
        const size_t rbase = (size_t)(row0 + (wr << 6) + (rb << 4) + m) * DD;
        #pragma unroll
        for (int i = 0; i < 8; ++i)
            Areg[rb][i] = *(const bf16x8*)(Abf + rbase + ((q + (i << 2)) << 3));
    }

    // ---- issue B loads for global chunk g=0 into buffer 0
    {
        const int col0 = (jg << 4) << 7;                 // jt=0
        const size_t pbase = (size_t)(col0 + srow + lr) * DD + (gch << 3);
        #pragma unroll
        for (int jj = 0; jj < 4; ++jj)
            gload16(Bbf + pbase + (size_t)(jj << 3) * DD,
                    &sB[0][(srow + (jj << 3)) << 6]);
    }
    __syncthreads();   // drains vmcnt: A regs + B chunk 0 ready

    const f32x4 fzero = {0.f, 0.f, 0.f, 0.f};
    f32x4 acc[4][4];
    #pragma unroll
    for (int a = 0; a < 4; ++a)
        #pragma unroll
        for (int b = 0; b < 4; ++b) acc[a][b] = fzero;

    float rpart = 0.0f;             // row partial, accumulated across all tiles

    for (int jt = 0; jt < 16; ++jt) {
        const int col0 = ((jg << 4) + jt) << 7;
        #pragma unroll
        for (int c = 0; c < 4; ++c) {
            const int g = (jt << 2) + c;
            // prefetch chunk g+1 into the other buffer
            if (g < 63) {
                const int gn = g + 1;
                const int ncol0 = ((jg << 4) + (gn >> 2)) << 7;
                const int nkb = (gn & 3) << 6;
                const size_t pbase = (size_t)(ncol0 + srow + lr) * DD + nkb + (gch << 3);
                u16* dst = &sB[1 - (c & 1)][0];
                #pragma unroll
                for (int jj = 0; jj < 4; ++jj)
                    gload16(Bbf + pbase + (size_t)(jj << 3) * DD,
                            &dst[(srow + (jj << 3)) << 6]);
            }
            // compute chunk g from buffer (c&1)
            const u16* buf = &sB[c & 1][0];
            #pragma unroll
            for (int s = 0; s < 2; ++s) {
                const int k8 = (s << 2) + q;
                bf16x8 bfv[4];
                #pragma unroll
                for (int cb = 0; cb < 4; ++cb) {
                    const int ccr = (wc << 6) + (cb << 4) + m;
                    bfv[cb] = *(const bf16x8*)(&buf[(ccr << 6) + ((k8 ^ (m & 7)) << 3)]);
                }
                #pragma unroll
                for (int rb = 0; rb < 4; ++rb)
                    #pragma unroll
                    for (int cb = 0; cb < 4; ++cb)
                        acc[rb][cb] = __builtin_amdgcn_mfma_f32_16x16x32_bf16(
                            Areg[rb][(c << 1) + s], bfv[cb], acc[rb][cb], 0, 0, 0);
            }
            __syncthreads();   // all waves done with buf; g+1 loads drained
        }

        // ---- per-tile epilogue (registers + global atomics only) ----
        // diag extraction (pre-exp): tile on the diagonal iff col0 == row0
        if (bi == ((jg << 4) + jt) && wr == wc) {
            #pragma unroll
            for (int rb = 0; rb < 4; ++rb)
                #pragma unroll
                for (int r = 0; r < 4; ++r)
                    if (m == ((q << 2) | r))
                        diag[row0 + (wr << 6) + (rb << 4) + m] = acc[rb][rb][r];
        }
        // exp2(l' - 144) in place; D layout: col = m, row = q*4 + r
        #pragma unroll
        for (int rb = 0; rb < 4; ++rb)
            #pragma unroll
            for (int cb = 0; cb < 4; ++cb)
                #pragma unroll
                for (int r = 0; r < 4; ++r)
                    acc[rb][cb][r] = __builtin_amdgcn_exp2f(acc[rb][cb][r] - 144.0f);

        // row partials: reduce 4 cb + 16-lane quad butterfly; lane m keeps
        // (rb=m>>2, r=m&3) for its own q -> fixed row per lane, accumulate.
        #pragma unroll
        for (int rb = 0; rb < 4; ++rb)
            #pragma unroll
            for (int r = 0; r < 4; ++r) {
                float v = acc[rb][0][r] + acc[rb][1][r] + acc[rb][2][r] + acc[rb][3][r];
                v += __shfl_xor(v, 1, 16);
                v += __shfl_xor(v, 2, 16);
                v += __shfl_xor(v, 4, 16);
                v += __shfl_xor(v, 8, 16);
                if (m == ((rb << 2) | r)) rpart += v;
            }

        // col partials: in-lane rb/r adds + cross-quad butterfly; lane (q,m)
        // keeps cb==q -> col = col0 + wc*64 + q*16 + m. One atomic per lane.
        float cpart = 0.0f;
        #pragma unroll
        for (int cb = 0; cb < 4; ++cb) {
            float v = 0.0f;
            #pragma unroll
            for (int rb = 0; rb < 4; ++rb)
                v += acc[rb][cb][0] + acc[rb][cb][1] + acc[rb][cb][2] + acc[rb][cb][3];
            v += __shfl_xor(v, 16, 64);
            v += __shfl_xor(v, 32, 64);
            if (q == cb) cpart = v;
        }
        atomicAdd(&s_col[col0 + (wc << 6) + (q << 4) + m], cpart);

        // re-zero accumulators for next tile
        #pragma unroll
        for (int a = 0; a < 4; ++a)
            #pragma unroll
            for (int b = 0; b < 4; ++b) acc[a][b] = fzero;
    }

    // row sums: one atomic per lane for the whole block
    atomicAdd(&s_row[row0 + (wr << 6) + ((m >> 2) << 4) + (q << 2) + (m & 3)], rpart);
}

// ---------- kernel 3: final reduce ----------
__global__ void final_kernel(const float* __restrict__ s_row, const float* __restrict__ s_col,
                             const float* __restrict__ diag, float* __restrict__ out) {
    __shared__ double red[256];
    int t = threadIdx.x;
    double p = 0.0;
    for (int i = t; i < NN; i += 256) {
        p += 0.5 * (double)(log2f(s_row[i]) + log2f(s_col[i])) + 144.0 - (double)diag[i];
    }
    red[t] = p;
    __syncthreads();
    for (int s = 128; s > 0; s >>= 1) {
        if (t < s) red[t] += red[t + s];
        __syncthreads();
    }
    if (t == 0) out[0] = (float)(red[0] * 0.6931471805599453 / (double)NN);
}

// ---------- launch ----------
extern "C" void kernel_launch(void* const* d_in, const int* in_sizes, int n_in,
                              void* d_out, int out_size, void* d_ws, size_t ws_size,
                              hipStream_t stream) {
    const float* img = (const float*)d_in[0];
    const float* txt = (const float*)d_in[1];
    char* ws = (char*)d_ws;
    u16*   Abf   = (u16*)ws;                               // 8 MB
    u16*   Bbf   = (u16*)(ws + 8388608);                   // 8 MB
    float* s_row = (float*)(ws + 16777216);                // 64 KB
    float* s_col = (float*)(ws + 16777216 + 65536);        // 64 KB
    float* diag  = (float*)(ws + 16777216 + 131072);       // 64 KB
    float* out   = (float*)d_out;

    prep_kernel<<<4096, 256, 0, stream>>>(img, txt, Abf, Bbf, s_row);
    gemm_lse_kernel<<<1024, 256, 0, stream>>>(Abf, Bbf, s_row, s_col, diag);
    final_kernel<<<1, 256, 0, stream>>>(s_row, s_col, diag, out);
}